// Round 19
// baseline (185.348 us; speedup 1.0000x reference)
//
#include <hip/hip_runtime.h>

#define N_NODES 10000
#define N_EDGES 320000
#define EL (N_EDGES + N_NODES)
#define HC 256
#define CAP 96

using bf16x8 = __attribute__((ext_vector_type(8))) short;
using f32x4  = __attribute__((ext_vector_type(4))) float;

__device__ __forceinline__ float bf2f(unsigned short u) {
  union { unsigned int i; float f; } v; v.i = ((unsigned int)u) << 16; return v.f;
}
__device__ __forceinline__ unsigned short f2bf(float f) {
  union { float f; unsigned int i; } v; v.f = f;
  unsigned int r = (v.i + 0x7FFFu + ((v.i >> 16) & 1u)) >> 16;
  return (unsigned short)r;
}

// ---------------- prep: zero cnt + transpose/convert 3 weight mats (328 blocks) --------

__device__ __forceinline__ void convw_body(const float* __restrict__ w,
                                           unsigned short* __restrict__ bt,
                                           int K, int idx) {
  int half = K >> 1;
  int col = idx / half;
  int k2 = (idx % half) * 2;
  ushort2 o;
  o.x = f2bf(w[(size_t)k2 * 256 + col]);
  o.y = f2bf(w[(size_t)(k2 + 1) * 256 + col]);
  *(ushort2*)(bt + (size_t)col * K + k2) = o;
}

__global__ __launch_bounds__(256) void prep_kernel(
    int* __restrict__ cnt,
    const float* __restrict__ w0, unsigned short* __restrict__ bt0,
    const float* __restrict__ w1, unsigned short* __restrict__ bt1,
    const float* __restrict__ w2, unsigned short* __restrict__ bt2) {
  int b = blockIdx.x, tid = threadIdx.x;
  if (b < 40) {
    int i = b * 256 + tid;
    if (i < N_NODES) cnt[i] = 0;
  } else if (b < 72) {
    convw_body(w0, bt0, 64, (b - 40) * 256 + tid);
  } else if (b < 200) {
    convw_body(w1, bt1, 256, (b - 72) * 256 + tid);
  } else {
    convw_body(w2, bt2, 256, (b - 200) * 256 + tid);
  }
}

// ---------------- MFMA phase with A already in LDS (K/64 slices of 2048B, XOR-swizzled) --

template <int K>
__device__ void mfma_from_lds(const char* ALds, char* Bsw,
                              const unsigned short* __restrict__ Bt,
                              unsigned short* __restrict__ Cb,
                              const float* __restrict__ att_src,
                              const float* __restrict__ att_dst,
                              float* __restrict__ asrc_out, float* __restrict__ adst_out,
                              int row0, int tid) {
  int wave = tid >> 6, lane = tid & 63;
  int r = lane & 15, g = lane >> 4;

  f32x4 acc[4];
#pragma unroll
  for (int i = 0; i < 4; ++i) acc[i] = {0.f, 0.f, 0.f, 0.f};

  for (int k0 = 0; k0 < K; k0 += 64) {
#pragma unroll
    for (int i = 0; i < 8; ++i) {  // stage B slice: 256 cols x 64 k bf16 (32KB)
      int idx = i * 256 + tid;
      int col = idx >> 3;
      int kc8 = idx & 7;
      uint4 v = *(const uint4*)(Bt + (size_t)col * K + k0 + kc8 * 8);
      *(uint4*)(Bsw + ((col * 128 + kc8 * 16) ^ ((col & 7) << 4))) = v;
    }
    __syncthreads();
    const char* Asl = ALds + (k0 >> 6) * 2048;
#pragma unroll
    for (int chunk = 0; chunk < 2; ++chunk) {
      bf16x8 af = *(const bf16x8*)(Asl + ((r * 128 + chunk * 64 + g * 16) ^ ((r & 7) << 4)));
#pragma unroll
      for (int i = 0; i < 4; ++i) {
        int col = (wave * 4 + i) * 16 + r;
        bf16x8 bfr = *(const bf16x8*)(Bsw + ((col * 128 + chunk * 64 + g * 16) ^ ((col & 7) << 4)));
        acc[i] = __builtin_amdgcn_mfma_f32_16x16x32_bf16(af, bfr, acc[i], 0, 0, 0);
      }
    }
    __syncthreads();
  }

  float asv[4], adv[4];
#pragma unroll
  for (int i = 0; i < 4; ++i) {
    int col = (wave * 4 + i) * 16 + r;
    asv[i] = att_src[col];
    adv[i] = att_dst[col];
  }
#pragma unroll
  for (int j = 0; j < 4; ++j) {
    float ps = acc[0][j] * asv[0] + acc[1][j] * asv[1] + acc[2][j] * asv[2] + acc[3][j] * asv[3];
    float pd = acc[0][j] * adv[0] + acc[1][j] * adv[1] + acc[2][j] * adv[2] + acc[3][j] * adv[3];
#pragma unroll
    for (int m = 8; m >= 1; m >>= 1) {
      ps += __shfl_xor(ps, m);
      pd += __shfl_xor(pd, m);
    }
    if (r == 0) {
      int row = row0 + g * 4 + j;
      asrc_out[row * 4 + wave] = ps;
      adst_out[row * 4 + wave] = pd;
    }
  }

#pragma unroll
  for (int i = 0; i < 4; ++i) {
    int col = (wave * 4 + i) * 16 + r;
#pragma unroll
    for (int j = 0; j < 4; ++j) {
      int row = row0 + g * 4 + j;
      Cb[(size_t)row * 256 + col] = f2bf(acc[i][j]);
    }
  }
}

// ---------------- node finish: softmax-div + bias + ELU + resid + LN -> v[4] ----------

template <int MODE>
__device__ __forceinline__ void finish_node(
    int n, int cb, float a0, float a1, float a2, float a3,
    float a4, float a5, float a6, float a7, float wsum, int half,
    const float* __restrict__ bias, const unsigned short* __restrict__ resid,
    const float* __restrict__ ln_g, const float* __restrict__ ln_b, float v[4]) {
  a0 += __shfl_xor(a0, 32); a1 += __shfl_xor(a1, 32);
  a2 += __shfl_xor(a2, 32); a3 += __shfl_xor(a3, 32);
  a4 += __shfl_xor(a4, 32); a5 += __shfl_xor(a5, 32);
  a6 += __shfl_xor(a6, 32); a7 += __shfl_xor(a7, 32);
  wsum += __shfl_xor(wsum, 32);

  float v0 = half ? a4 : a0;
  float v1 = half ? a5 : a1;
  float v2 = half ? a6 : a2;
  float v3 = half ? a7 : a3;

  float rw = 1.f / wsum;
  float4 b4 = *(const float4*)(bias + cb);
  v0 = fmaf(v0, rw, b4.x);
  v1 = fmaf(v1, rw, b4.y);
  v2 = fmaf(v2, rw, b4.z);
  v3 = fmaf(v3, rw, b4.w);
  v0 = v0 > 0.f ? v0 : __expf(v0) - 1.f;
  v1 = v1 > 0.f ? v1 : __expf(v1) - 1.f;
  v2 = v2 > 0.f ? v2 : __expf(v2) - 1.f;
  v3 = v3 > 0.f ? v3 : __expf(v3) - 1.f;

  if constexpr (MODE == 0) {
    if (cb < 64) {
      ushort4 r4 = *(const ushort4*)(resid + (size_t)n * 64 + cb);
      v0 += bf2f(r4.x); v1 += bf2f(r4.y); v2 += bf2f(r4.z); v3 += bf2f(r4.w);
    }
  } else {
    ushort4 r4 = *(const ushort4*)(resid + (size_t)n * HC + cb);
    v0 += bf2f(r4.x); v1 += bf2f(r4.y); v2 += bf2f(r4.z); v3 += bf2f(r4.w);
  }

  float s1 = v0 + v1 + v2 + v3;
  float s2 = v0 * v0 + v1 * v1 + v2 * v2 + v3 * v3;
#pragma unroll
  for (int m = 32; m >= 1; m >>= 1) {
    s1 += __shfl_xor(s1, m);
    s2 += __shfl_xor(s2, m);
  }
  float mean = s1 * (1.f / 256.f);
  float var = s2 * (1.f / 256.f) - mean * mean;
  float inv = rsqrtf(var + 1e-5f);

  float4 g4 = *(const float4*)(ln_g + cb);
  float4 lb4 = *(const float4*)(ln_b + cb);
  v[0] = (v0 - mean) * inv * g4.x + lb4.x;
  v[1] = (v1 - mean) * inv * g4.y + lb4.y;
  v[2] = (v2 - mean) * inv * g4.z + lb4.z;
  v[3] = (v3 - mean) * inv * g4.w + lb4.w;
}

// ---------------- agg for TWO nodes, edge loops interleaved (2x MLP) ----------------
// Per-node math order identical to single-node version -> bitwise-same results.

template <int MODE>
__device__ __forceinline__ void agg_pair_compute(
    int n0, int n1, int lane,
    const int* __restrict__ cnt, const int* __restrict__ slots,
    const float* __restrict__ asrc, const float* __restrict__ adst,
    const unsigned short* __restrict__ xb, const float* __restrict__ bias,
    const unsigned short* __restrict__ resid,
    const float* __restrict__ ln_g, const float* __restrict__ ln_b,
    float vA[4], float vB[4], int& cbOut) {
  int lh = lane & 31;
  int half = lane >> 5;
  int h = lh >> 3;
  int ch8 = lh << 3;
  float adA = adst[n0 * 4 + h];
  float adB = adst[n1 * 4 + h];

  int degA = cnt[n0], degB = cnt[n1];
  int lenA = (degA + 1) >> 1, lenB = (degB + 1) >> 1;
  int begA = n0 * CAP + (half ? lenA : 0), endA = n0 * CAP + (half ? degA : lenA);
  int begB = n1 * CAP + (half ? lenB : 0), endB = n1 * CAP + (half ? degB : lenB);
  int lastA = endA - 1, lastB = endB - 1;

  float aA0 = 0.f, aA1 = 0.f, aA2 = 0.f, aA3 = 0.f, aA4 = 0.f, aA5 = 0.f, aA6 = 0.f, aA7 = 0.f;
  float aB0 = 0.f, aB1 = 0.f, aB2 = 0.f, aB3 = 0.f, aB4 = 0.f, aB5 = 0.f, aB6 = 0.f, aB7 = 0.f;
  float wsumA = 0.f, wsumB = 0.f;

  int sA0[4], sA1[4];
#pragma unroll
  for (int j = 0; j < 4; ++j) {
    sA0[j] = slots[min(begA + j, lastA)];
    sA1[j] = slots[min(begB + j, lastB)];
  }
  float ca0[4], ca1[4]; uint4 cx0[4], cx1[4];
#pragma unroll
  for (int j = 0; j < 4; ++j) {
    ca0[j] = asrc[sA0[j] * 4 + h];
    cx0[j] = *(const uint4*)(xb + (size_t)sA0[j] * HC + ch8);
    ca1[j] = asrc[sA1[j] * 4 + h];
    cx1[j] = *(const uint4*)(xb + (size_t)sA1[j] * HC + ch8);
  }
#pragma unroll
  for (int j = 0; j < 4; ++j) {
    sA0[j] = slots[min(begA + 4 + j, lastA)];
    sA1[j] = slots[min(begB + 4 + j, lastB)];
  }

  int baseA = begA, baseB = begB;
  while (baseA < endA || baseB < endB) {
    float na0[4], na1[4]; uint4 nx0[4], nx1[4];
#pragma unroll
    for (int j = 0; j < 4; ++j) {
      na0[j] = asrc[sA0[j] * 4 + h];
      nx0[j] = *(const uint4*)(xb + (size_t)sA0[j] * HC + ch8);
      na1[j] = asrc[sA1[j] * 4 + h];
      nx1[j] = *(const uint4*)(xb + (size_t)sA1[j] * HC + ch8);
    }
#pragma unroll
    for (int j = 0; j < 4; ++j) {
      sA0[j] = slots[min(baseA + 8 + j, lastA)];
      sA1[j] = slots[min(baseB + 8 + j, lastB)];
    }
#pragma unroll
    for (int j = 0; j < 4; ++j) {
      float eA = ca0[j] + adA;
      eA = eA > 0.f ? eA : 0.2f * eA;
      float wgA = __expf(eA);
      wgA = (baseA + j < endA) ? wgA : 0.f;
      wsumA += wgA;
      aA0 = fmaf(wgA, bf2f((unsigned short)(cx0[j].x & 0xffff)), aA0);
      aA1 = fmaf(wgA, bf2f((unsigned short)(cx0[j].x >> 16)), aA1);
      aA2 = fmaf(wgA, bf2f((unsigned short)(cx0[j].y & 0xffff)), aA2);
      aA3 = fmaf(wgA, bf2f((unsigned short)(cx0[j].y >> 16)), aA3);
      aA4 = fmaf(wgA, bf2f((unsigned short)(cx0[j].z & 0xffff)), aA4);
      aA5 = fmaf(wgA, bf2f((unsigned short)(cx0[j].z >> 16)), aA5);
      aA6 = fmaf(wgA, bf2f((unsigned short)(cx0[j].w & 0xffff)), aA6);
      aA7 = fmaf(wgA, bf2f((unsigned short)(cx0[j].w >> 16)), aA7);

      float eB = ca1[j] + adB;
      eB = eB > 0.f ? eB : 0.2f * eB;
      float wgB = __expf(eB);
      wgB = (baseB + j < endB) ? wgB : 0.f;
      wsumB += wgB;
      aB0 = fmaf(wgB, bf2f((unsigned short)(cx1[j].x & 0xffff)), aB0);
      aB1 = fmaf(wgB, bf2f((unsigned short)(cx1[j].x >> 16)), aB1);
      aB2 = fmaf(wgB, bf2f((unsigned short)(cx1[j].y & 0xffff)), aB2);
      aB3 = fmaf(wgB, bf2f((unsigned short)(cx1[j].y >> 16)), aB3);
      aB4 = fmaf(wgB, bf2f((unsigned short)(cx1[j].z & 0xffff)), aB4);
      aB5 = fmaf(wgB, bf2f((unsigned short)(cx1[j].z >> 16)), aB5);
      aB6 = fmaf(wgB, bf2f((unsigned short)(cx1[j].w & 0xffff)), aB6);
      aB7 = fmaf(wgB, bf2f((unsigned short)(cx1[j].w >> 16)), aB7);
    }
#pragma unroll
    for (int j = 0; j < 4; ++j) {
      ca0[j] = na0[j]; cx0[j] = nx0[j];
      ca1[j] = na1[j]; cx1[j] = nx1[j];
    }
    baseA += 4; baseB += 4;
  }

  int cb = ch8 + half * 4;
  finish_node<MODE>(n0, cb, aA0, aA1, aA2, aA3, aA4, aA5, aA6, aA7, wsumA, half,
                    bias, resid, ln_g, ln_b, vA);
  finish_node<MODE>(n1, cb, aB0, aB1, aB2, aB3, aB4, aB5, aB6, aB7, wsumB, half,
                    bias, resid, ln_g, ln_b, vB);
  cbOut = cb;
}

// ---------------- dispatch 2: edge scatter + fused lin->mfma0 ----------------

__global__ __launch_bounds__(256) void scatter_linmfma(
    const int* __restrict__ edges, int* __restrict__ cnt, int* __restrict__ slots,
    const float* __restrict__ x, const float* __restrict__ lin_w,
    const float* __restrict__ lin_b, unsigned short* __restrict__ h0,
    const unsigned short* __restrict__ bt0,
    const float* __restrict__ as0, const float* __restrict__ ad0,
    unsigned short* __restrict__ xbA, float* __restrict__ as4A, float* __restrict__ ad4A) {
  __shared__ __align__(16) char smem[34816];
  int tid = threadIdx.x;
  int b = blockIdx.x;
  if (b < 1290) {
    int e = b * 256 + tid;
    if (e >= EL) return;
    int s, d;
    if (e < N_EDGES) { s = edges[e]; d = edges[N_EDGES + e]; }
    else { s = d = e - N_EDGES; }
    int pos = atomicAdd(&cnt[d], 1);
    slots[d * CAP + pos] = s;
    return;
  }
  int row0 = (b - 1290) * 16;
  int g = tid >> 6, lane = tid & 63;
  {
    float (*As)[36] = (float(*)[36])(smem + 2048);
    float (*Bs)[64] = (float(*)[64])(smem + 2048 + 2304);
    float acc[4] = {0.f, 0.f, 0.f, 0.f};
    for (int k0 = 0; k0 < 64; k0 += 32) {
      if (tid < 128) {
        int r = tid >> 3;
        int kc = (tid & 7) << 2;
        *(float4*)&As[r][kc] = *(const float4*)(x + (size_t)(row0 + r) * 64 + k0 + kc);
      }
#pragma unroll
      for (int i = 0; i < 2; ++i) {
        int fidx = (i * 256 + tid) * 4;
        *(float4*)&Bs[fidx >> 6][fidx & 63] =
            *(const float4*)(lin_w + (size_t)(k0 + (fidx >> 6)) * 64 + (fidx & 63));
      }
      __syncthreads();
#pragma unroll
      for (int kk = 0; kk < 32; kk += 4) {
        float a4[4][4];
#pragma unroll
        for (int rr = 0; rr < 4; ++rr) {
          float4 t = *(const float4*)&As[g * 4 + rr][kk];
          a4[rr][0] = t.x; a4[rr][1] = t.y; a4[rr][2] = t.z; a4[rr][3] = t.w;
        }
#pragma unroll
        for (int u = 0; u < 4; ++u) {
          float bb = Bs[kk + u][lane];
#pragma unroll
          for (int rr = 0; rr < 4; ++rr) acc[rr] = fmaf(a4[rr][u], bb, acc[rr]);
        }
      }
      __syncthreads();
    }
    float bl = lin_b[lane];
#pragma unroll
    for (int rr = 0; rr < 4; ++rr) {
      int r = g * 4 + rr;
      unsigned short hv = f2bf(fmaxf(acc[rr] + bl, 0.f));
      h0[(size_t)(row0 + r) * 64 + lane] = hv;
      *(unsigned short*)(smem + ((r * 128 + lane * 2) ^ ((r & 7) << 4))) = hv;
    }
  }
  __syncthreads();
  mfma_from_lds<64>(smem, smem + 2048, bt0, xbA, as0, ad0, as4A, ad4A, row0, tid);
}

// ---------------- dispatch 3/4: fused agg(L) -> mfma(L+1), pair-interleaved agg --------

template <int MODE>
__global__ __launch_bounds__(256) void aggmfma_kernel(
    const int* __restrict__ cnt, const int* __restrict__ slots,
    const float* __restrict__ asrcIn, const float* __restrict__ adstIn,
    const unsigned short* __restrict__ xbIn, const float* __restrict__ gbias,
    const unsigned short* __restrict__ resid, const float* __restrict__ ln_g,
    const float* __restrict__ ln_b, unsigned short* __restrict__ hOut,
    const unsigned short* __restrict__ Bt, unsigned short* __restrict__ xbOut,
    const float* __restrict__ att_src, const float* __restrict__ att_dst,
    float* __restrict__ asrcOut, float* __restrict__ adstOut) {
  __shared__ __align__(16) char smem[40960];  // ALds 8KB @0; Bsw 32KB @8192
  int tid = threadIdx.x;
  int wave = tid >> 6, lane = tid & 63;
  int row0 = blockIdx.x * 16;

#pragma unroll
  for (int pp = 0; pp < 2; ++pp) {
    int r0 = wave * 4 + pp * 2;
    int n0 = row0 + r0, n1 = n0 + 1;
    float vA[4], vB[4]; int cb;
    agg_pair_compute<MODE>(n0, n1, lane, cnt, slots, asrcIn, adstIn, xbIn, gbias,
                           resid, ln_g, ln_b, vA, vB, cb);
    ushort4 oA, oB;
    oA.x = f2bf(vA[0]); oA.y = f2bf(vA[1]); oA.z = f2bf(vA[2]); oA.w = f2bf(vA[3]);
    oB.x = f2bf(vB[0]); oB.y = f2bf(vB[1]); oB.z = f2bf(vB[2]); oB.w = f2bf(vB[3]);
    *(ushort4*)(hOut + (size_t)n0 * HC + cb) = oA;
    *(ushort4*)(hOut + (size_t)n1 * HC + cb) = oB;
    *(ushort4*)(smem + (cb >> 6) * 2048 + ((r0 * 128 + (cb & 63) * 2) ^ ((r0 & 7) << 4))) = oA;
    int r1 = r0 + 1;
    *(ushort4*)(smem + (cb >> 6) * 2048 + ((r1 * 128 + (cb & 63) * 2) ^ ((r1 & 7) << 4))) = oB;
  }
  __syncthreads();
  mfma_from_lds<256>(smem, smem + 8192, Bt, xbOut, att_src, att_dst,
                     asrcOut, adstOut, row0, tid);
}

// ---------------- dispatch 5: fused agg(layer2) -> FFN, pair-interleaved agg ----------

__global__ __launch_bounds__(256) void aggffn_kernel(
    const int* __restrict__ cnt, const int* __restrict__ slots,
    const float* __restrict__ asrcIn, const float* __restrict__ adstIn,
    const unsigned short* __restrict__ xbIn, const float* __restrict__ gbias,
    const unsigned short* __restrict__ resid, const float* __restrict__ ln_g,
    const float* __restrict__ ln_b,
    const float* __restrict__ w1, const float* __restrict__ b1,
    const float* __restrict__ w2, const float* __restrict__ b2,
    float* __restrict__ out) {
  __shared__ __align__(16) char smem[41216];
  float (*AF)[256] = (float(*)[256])smem;            // 16KB
  float (*Bs)[128] = (float(*)[128])(smem + 16384);  // 16KB
  float (*Ms)[132] = (float(*)[132])(smem + 32768);  // 8448B
  int tid = threadIdx.x;
  int wave = tid >> 6, lane = tid & 63;
  int row0 = blockIdx.x * 16;

#pragma unroll
  for (int pp = 0; pp < 2; ++pp) {
    int r0 = wave * 4 + pp * 2;
    int n0 = row0 + r0, n1 = n0 + 1;
    float vA[4], vB[4]; int cb;
    agg_pair_compute<1>(n0, n1, lane, cnt, slots, asrcIn, adstIn, xbIn, gbias,
                        resid, ln_g, ln_b, vA, vB, cb);
    *(float4*)&AF[r0][cb] = make_float4(vA[0], vA[1], vA[2], vA[3]);
    *(float4*)&AF[r0 + 1][cb] = make_float4(vB[0], vB[1], vB[2], vB[3]);
  }
  __syncthreads();

  int g = wave;
  {  // phase 1: Ms[16][128] = relu(AF @ w1 + b1)
    int colBase = lane * 2;
    float acc[4][2];
#pragma unroll
    for (int r = 0; r < 4; ++r) { acc[r][0] = 0.f; acc[r][1] = 0.f; }
    for (int k0 = 0; k0 < 256; k0 += 32) {
#pragma unroll
      for (int i = 0; i < 4; ++i) {
        int fidx = (i * 256 + tid) * 4;
        *(float4*)&Bs[fidx >> 7][fidx & 127] =
            *(const float4*)(w1 + (size_t)(k0 + (fidx >> 7)) * 128 + (fidx & 127));
      }
      __syncthreads();
#pragma unroll
      for (int kk = 0; kk < 32; kk += 4) {
        float a4[4][4];
#pragma unroll
        for (int rr = 0; rr < 4; ++rr) {
          float4 tv = *(const float4*)&AF[g * 4 + rr][k0 + kk];
          a4[rr][0] = tv.x; a4[rr][1] = tv.y; a4[rr][2] = tv.z; a4[rr][3] = tv.w;
        }
#pragma unroll
        for (int u = 0; u < 4; ++u) {
          float2 b = *(const float2*)&Bs[kk + u][colBase];
#pragma unroll
          for (int rr = 0; rr < 4; ++rr) {
            acc[rr][0] = fmaf(a4[rr][u], b.x, acc[rr][0]);
            acc[rr][1] = fmaf(a4[rr][u], b.y, acc[rr][1]);
          }
        }
      }
      __syncthreads();
    }
    float bb0 = b1[colBase], bb1 = b1[colBase + 1];
#pragma unroll
    for (int rr = 0; rr < 4; ++rr) {
      Ms[g * 4 + rr][colBase]     = fmaxf(acc[rr][0] + bb0, 0.f);
      Ms[g * 4 + rr][colBase + 1] = fmaxf(acc[rr][1] + bb1, 0.f);
    }
  }
  __syncthreads();

  {  // phase 2: out[16][64] = Ms @ w2 + b2
    float acc[4] = {0.f, 0.f, 0.f, 0.f};
    for (int k0 = 0; k0 < 128; k0 += 32) {
#pragma unroll
      for (int i = 0; i < 2; ++i) {
        int fidx = (i * 256 + tid) * 4;
        *(float4*)&Bs[fidx >> 6][fidx & 63] =
            *(const float4*)(w2 + (size_t)(k0 + (fidx >> 6)) * 64 + (fidx & 63));
      }
      __syncthreads();
#pragma unroll
      for (int kk = 0; kk < 32; ++kk) {
        float b = Bs[kk][lane];
#pragma unroll
        for (int rr = 0; rr < 4; ++rr)
          acc[rr] = fmaf(Ms[g * 4 + rr][k0 + kk], b, acc[rr]);
      }
      __syncthreads();
    }
    float bb = b2[lane];
#pragma unroll
    for (int rr = 0; rr < 4; ++rr) {
      int row = row0 + g * 4 + rr;
      out[(size_t)row * 64 + lane] = acc[rr] + bb;
    }
  }
}

// ---------------- launch ----------------

extern "C" void kernel_launch(void* const* d_in, const int* in_sizes, int n_in,
                              void* d_out, int out_size, void* d_ws, size_t ws_size,
                              hipStream_t stream) {
  (void)in_sizes; (void)n_in; (void)out_size; (void)ws_size;
  const float* x      = (const float*)d_in[0];
  const int*   edges  = (const int*)d_in[1];
  const float* lin_w  = (const float*)d_in[2];
  const float* lin_b  = (const float*)d_in[3];
  const float* gat_w[3] = {(const float*)d_in[4], (const float*)d_in[10], (const float*)d_in[16]};
  const float* att_s[3] = {(const float*)d_in[5], (const float*)d_in[11], (const float*)d_in[17]};
  const float* att_d[3] = {(const float*)d_in[6], (const float*)d_in[12], (const float*)d_in[18]};
  const float* gat_b[3] = {(const float*)d_in[7], (const float*)d_in[13], (const float*)d_in[19]};
  const float* ln_g[3]  = {(const float*)d_in[8], (const float*)d_in[14], (const float*)d_in[20]};
  const float* ln_b[3]  = {(const float*)d_in[9], (const float*)d_in[15], (const float*)d_in[21]};
  const float* ffn_w1 = (const float*)d_in[22];
  const float* ffn_b1 = (const float*)d_in[23];
  const float* ffn_w2 = (const float*)d_in[24];
  const float* ffn_b2 = (const float*)d_in[25];

  char* p = (char*)d_ws;
  auto alloc = [&](size_t bytes) {
    char* q = p;
    p += (bytes + 255) & ~(size_t)255;
    return q;
  };
  int* cnt   = (int*)alloc(N_NODES * 4);
  int* slots = (int*)alloc((size_t)N_NODES * CAP * 4);
  unsigned short* h0 = (unsigned short*)alloc((size_t)N_NODES * 64 * 2);
  unsigned short* hA = (unsigned short*)alloc((size_t)N_NODES * HC * 2);
  unsigned short* hB = (unsigned short*)alloc((size_t)N_NODES * HC * 2);
  unsigned short* xbA = (unsigned short*)alloc((size_t)N_NODES * HC * 2);
  unsigned short* xbB = (unsigned short*)alloc((size_t)N_NODES * HC * 2);
  float* as4A = (float*)alloc((size_t)N_NODES * 16);
  float* ad4A = (float*)alloc((size_t)N_NODES * 16);
  float* as4B = (float*)alloc((size_t)N_NODES * 16);
  float* ad4B = (float*)alloc((size_t)N_NODES * 16);
  unsigned short* bt0 = (unsigned short*)alloc(256 * 64 * 2);
  unsigned short* bt1 = (unsigned short*)alloc(256 * 256 * 2);
  unsigned short* bt2 = (unsigned short*)alloc(256 * 256 * 2);

  const int gblk = N_NODES / 16;  // 625

  prep_kernel<<<328, 256, 0, stream>>>(cnt, gat_w[0], bt0, gat_w[1], bt1, gat_w[2], bt2);
  scatter_linmfma<<<1290 + gblk, 256, 0, stream>>>(edges, cnt, slots, x, lin_w, lin_b,
                                                   h0, bt0, att_s[0], att_d[0],
                                                   xbA, as4A, ad4A);
  aggmfma_kernel<0><<<gblk, 256, 0, stream>>>(cnt, slots, as4A, ad4A, xbA, gat_b[0],
                                              h0, ln_g[0], ln_b[0], hA,
                                              bt1, xbB, att_s[1], att_d[1], as4B, ad4B);
  aggmfma_kernel<1><<<gblk, 256, 0, stream>>>(cnt, slots, as4B, ad4B, xbB, gat_b[1],
                                              hA, ln_g[1], ln_b[1], hB,
                                              bt2, xbA, att_s[2], att_d[2], as4A, ad4A);
  aggffn_kernel<<<gblk, 256, 0, stream>>>(cnt, slots, as4A, ad4A, xbA, gat_b[2],
                                          hB, ln_g[2], ln_b[2],
                                          ffn_w1, ffn_b1, ffn_w2, ffn_b2, (float*)d_out);
}

// Round 21
// 151.509 us; speedup vs baseline: 1.2233x; 1.2233x over previous
//
#include <hip/hip_runtime.h>

#define N_NODES 10000
#define N_EDGES 320000
#define EL (N_EDGES + N_NODES)
#define HC 256
#define CAP 96

using bf16x8 = __attribute__((ext_vector_type(8))) short;
using f32x4  = __attribute__((ext_vector_type(4))) float;

__device__ __forceinline__ float bf2f(unsigned short u) {
  union { unsigned int i; float f; } v; v.i = ((unsigned int)u) << 16; return v.f;
}
__device__ __forceinline__ unsigned short f2bf(float f) {
  union { float f; unsigned int i; } v; v.f = f;
  unsigned int r = (v.i + 0x7FFFu + ((v.i >> 16) & 1u)) >> 16;
  return (unsigned short)r;
}

// ---------------- prep: zero cnt + transpose/convert 3 weight mats (328 blocks) --------

__device__ __forceinline__ void convw_body(const float* __restrict__ w,
                                           unsigned short* __restrict__ bt,
                                           int K, int idx) {
  int half = K >> 1;
  int col = idx / half;
  int k2 = (idx % half) * 2;
  ushort2 o;
  o.x = f2bf(w[(size_t)k2 * 256 + col]);
  o.y = f2bf(w[(size_t)(k2 + 1) * 256 + col]);
  *(ushort2*)(bt + (size_t)col * K + k2) = o;
}

__global__ __launch_bounds__(256) void prep_kernel(
    int* __restrict__ cnt,
    const float* __restrict__ w0, unsigned short* __restrict__ bt0,
    const float* __restrict__ w1, unsigned short* __restrict__ bt1,
    const float* __restrict__ w2, unsigned short* __restrict__ bt2) {
  int b = blockIdx.x, tid = threadIdx.x;
  if (b < 40) {
    int i = b * 256 + tid;
    if (i < N_NODES) cnt[i] = 0;
  } else if (b < 72) {
    convw_body(w0, bt0, 64, (b - 40) * 256 + tid);
  } else if (b < 200) {
    convw_body(w1, bt1, 256, (b - 72) * 256 + tid);
  } else {
    convw_body(w2, bt2, 256, (b - 200) * 256 + tid);
  }
}

// ---------------- MFMA phase with A already in LDS (K/64 slices of 2048B, XOR-swizzled) --

template <int K>
__device__ void mfma_from_lds(const char* ALds, char* Bsw,
                              const unsigned short* __restrict__ Bt,
                              unsigned short* __restrict__ Cb,
                              const float* __restrict__ att_src,
                              const float* __restrict__ att_dst,
                              float* __restrict__ asrc_out, float* __restrict__ adst_out,
                              int row0, int tid) {
  int wave = tid >> 6, lane = tid & 63;
  int r = lane & 15, g = lane >> 4;

  f32x4 acc[4];
#pragma unroll
  for (int i = 0; i < 4; ++i) acc[i] = {0.f, 0.f, 0.f, 0.f};

  for (int k0 = 0; k0 < K; k0 += 64) {
#pragma unroll
    for (int i = 0; i < 8; ++i) {  // stage B slice: 256 cols x 64 k bf16 (32KB)
      int idx = i * 256 + tid;
      int col = idx >> 3;
      int kc8 = idx & 7;
      uint4 v = *(const uint4*)(Bt + (size_t)col * K + k0 + kc8 * 8);
      *(uint4*)(Bsw + ((col * 128 + kc8 * 16) ^ ((col & 7) << 4))) = v;
    }
    __syncthreads();
    const char* Asl = ALds + (k0 >> 6) * 2048;
#pragma unroll
    for (int chunk = 0; chunk < 2; ++chunk) {
      bf16x8 af = *(const bf16x8*)(Asl + ((r * 128 + chunk * 64 + g * 16) ^ ((r & 7) << 4)));
#pragma unroll
      for (int i = 0; i < 4; ++i) {
        int col = (wave * 4 + i) * 16 + r;
        bf16x8 bfr = *(const bf16x8*)(Bsw + ((col * 128 + chunk * 64 + g * 16) ^ ((col & 7) << 4)));
        acc[i] = __builtin_amdgcn_mfma_f32_16x16x32_bf16(af, bfr, acc[i], 0, 0, 0);
      }
    }
    __syncthreads();
  }

  float asv[4], adv[4];
#pragma unroll
  for (int i = 0; i < 4; ++i) {
    int col = (wave * 4 + i) * 16 + r;
    asv[i] = att_src[col];
    adv[i] = att_dst[col];
  }
#pragma unroll
  for (int j = 0; j < 4; ++j) {
    float ps = acc[0][j] * asv[0] + acc[1][j] * asv[1] + acc[2][j] * asv[2] + acc[3][j] * asv[3];
    float pd = acc[0][j] * adv[0] + acc[1][j] * adv[1] + acc[2][j] * adv[2] + acc[3][j] * adv[3];
#pragma unroll
    for (int m = 8; m >= 1; m >>= 1) {
      ps += __shfl_xor(ps, m);
      pd += __shfl_xor(pd, m);
    }
    if (r == 0) {
      int row = row0 + g * 4 + j;
      asrc_out[row * 4 + wave] = ps;
      adst_out[row * 4 + wave] = pd;
    }
  }

#pragma unroll
  for (int i = 0; i < 4; ++i) {
    int col = (wave * 4 + i) * 16 + r;
#pragma unroll
    for (int j = 0; j < 4; ++j) {
      int row = row0 + g * 4 + j;
      Cb[(size_t)row * 256 + col] = f2bf(acc[i][j]);
    }
  }
}

// ---------------- agg for ONE node (full wave; half-wave edge split; chunk-4) ----------
// Returns post-LN values v[0..3] for channels cbOut..cbOut+3.

template <int MODE>
__device__ __forceinline__ void agg_node_compute(
    int n, int lane,
    const int* __restrict__ cnt, const int* __restrict__ slots,
    const float* __restrict__ asrc, const float* __restrict__ adst,
    const unsigned short* __restrict__ xb, const float* __restrict__ bias,
    const unsigned short* __restrict__ resid,
    const float* __restrict__ ln_g, const float* __restrict__ ln_b,
    float v[4], int& cbOut) {
  int lh = lane & 31;
  int half = lane >> 5;
  int h = lh >> 3;
  int ch8 = lh << 3;
  float ad = adst[n * 4 + h];

  int i0 = n * CAP;
  int deg = cnt[n];
  int len0 = (deg + 1) >> 1;
  int beg = i0 + (half ? len0 : 0);
  int end = i0 + (half ? deg : len0);
  int last = end - 1;

  float a0 = 0.f, a1 = 0.f, a2 = 0.f, a3 = 0.f, a4 = 0.f, a5 = 0.f, a6 = 0.f, a7 = 0.f;
  float wsum = 0.f;

  int sA[4];
#pragma unroll
  for (int j = 0; j < 4; ++j) sA[j] = slots[min(beg + j, last)];
  float ca[4]; uint4 cx[4];
#pragma unroll
  for (int j = 0; j < 4; ++j) {
    ca[j] = asrc[sA[j] * 4 + h];
    cx[j] = *(const uint4*)(xb + (size_t)sA[j] * HC + ch8);
  }
#pragma unroll
  for (int j = 0; j < 4; ++j) sA[j] = slots[min(beg + 4 + j, last)];

  for (int base = beg; base < end; base += 4) {
    float na[4]; uint4 nx[4];
#pragma unroll
    for (int j = 0; j < 4; ++j) {
      na[j] = asrc[sA[j] * 4 + h];
      nx[j] = *(const uint4*)(xb + (size_t)sA[j] * HC + ch8);
    }
#pragma unroll
    for (int j = 0; j < 4; ++j) sA[j] = slots[min(base + 8 + j, last)];
#pragma unroll
    for (int j = 0; j < 4; ++j) {
      float e = ca[j] + ad;
      e = e > 0.f ? e : 0.2f * e;
      float wg = __expf(e);
      wg = (base + j < end) ? wg : 0.f;
      wsum += wg;
      a0 = fmaf(wg, bf2f((unsigned short)(cx[j].x & 0xffff)), a0);
      a1 = fmaf(wg, bf2f((unsigned short)(cx[j].x >> 16)), a1);
      a2 = fmaf(wg, bf2f((unsigned short)(cx[j].y & 0xffff)), a2);
      a3 = fmaf(wg, bf2f((unsigned short)(cx[j].y >> 16)), a3);
      a4 = fmaf(wg, bf2f((unsigned short)(cx[j].z & 0xffff)), a4);
      a5 = fmaf(wg, bf2f((unsigned short)(cx[j].z >> 16)), a5);
      a6 = fmaf(wg, bf2f((unsigned short)(cx[j].w & 0xffff)), a6);
      a7 = fmaf(wg, bf2f((unsigned short)(cx[j].w >> 16)), a7);
    }
#pragma unroll
    for (int j = 0; j < 4; ++j) { ca[j] = na[j]; cx[j] = nx[j]; }
  }

  a0 += __shfl_xor(a0, 32); a1 += __shfl_xor(a1, 32);
  a2 += __shfl_xor(a2, 32); a3 += __shfl_xor(a3, 32);
  a4 += __shfl_xor(a4, 32); a5 += __shfl_xor(a5, 32);
  a6 += __shfl_xor(a6, 32); a7 += __shfl_xor(a7, 32);
  wsum += __shfl_xor(wsum, 32);

  int cb = ch8 + half * 4;
  float v0 = half ? a4 : a0;
  float v1 = half ? a5 : a1;
  float v2 = half ? a6 : a2;
  float v3 = half ? a7 : a3;

  float rw = 1.f / wsum;
  float4 b4 = *(const float4*)(bias + cb);
  v0 = fmaf(v0, rw, b4.x);
  v1 = fmaf(v1, rw, b4.y);
  v2 = fmaf(v2, rw, b4.z);
  v3 = fmaf(v3, rw, b4.w);
  v0 = v0 > 0.f ? v0 : __expf(v0) - 1.f;
  v1 = v1 > 0.f ? v1 : __expf(v1) - 1.f;
  v2 = v2 > 0.f ? v2 : __expf(v2) - 1.f;
  v3 = v3 > 0.f ? v3 : __expf(v3) - 1.f;

  if constexpr (MODE == 0) {
    if (cb < 64) {
      ushort4 r4 = *(const ushort4*)(resid + (size_t)n * 64 + cb);
      v0 += bf2f(r4.x); v1 += bf2f(r4.y); v2 += bf2f(r4.z); v3 += bf2f(r4.w);
    }
  } else {
    ushort4 r4 = *(const ushort4*)(resid + (size_t)n * HC + cb);
    v0 += bf2f(r4.x); v1 += bf2f(r4.y); v2 += bf2f(r4.z); v3 += bf2f(r4.w);
  }

  float s1 = v0 + v1 + v2 + v3;
  float s2 = v0 * v0 + v1 * v1 + v2 * v2 + v3 * v3;
#pragma unroll
  for (int m = 32; m >= 1; m >>= 1) {
    s1 += __shfl_xor(s1, m);
    s2 += __shfl_xor(s2, m);
  }
  float mean = s1 * (1.f / 256.f);
  float var = s2 * (1.f / 256.f) - mean * mean;
  float inv = rsqrtf(var + 1e-5f);

  float4 g4 = *(const float4*)(ln_g + cb);
  float4 lb4 = *(const float4*)(ln_b + cb);
  v[0] = (v0 - mean) * inv * g4.x + lb4.x;
  v[1] = (v1 - mean) * inv * g4.y + lb4.y;
  v[2] = (v2 - mean) * inv * g4.z + lb4.z;
  v[3] = (v3 - mean) * inv * g4.w + lb4.w;
  cbOut = cb;
}

// ---------------- dispatch 2: edge scatter + fused lin->mfma0 ----------------

__global__ __launch_bounds__(256) void scatter_linmfma(
    const int* __restrict__ edges, int* __restrict__ cnt, int* __restrict__ slots,
    const float* __restrict__ x, const float* __restrict__ lin_w,
    const float* __restrict__ lin_b, unsigned short* __restrict__ h0,
    const unsigned short* __restrict__ bt0,
    const float* __restrict__ as0, const float* __restrict__ ad0,
    unsigned short* __restrict__ xbA, float* __restrict__ as4A, float* __restrict__ ad4A) {
  __shared__ __align__(16) char smem[34816];
  int tid = threadIdx.x;
  int b = blockIdx.x;
  if (b < 1290) {
    int e = b * 256 + tid;
    if (e >= EL) return;
    int s, d;
    if (e < N_EDGES) { s = edges[e]; d = edges[N_EDGES + e]; }
    else { s = d = e - N_EDGES; }
    int pos = atomicAdd(&cnt[d], 1);
    slots[d * CAP + pos] = s;
    return;
  }
  int row0 = (b - 1290) * 16;
  int g = tid >> 6, lane = tid & 63;
  {
    float (*As)[36] = (float(*)[36])(smem + 2048);
    float (*Bs)[64] = (float(*)[64])(smem + 2048 + 2304);
    float acc[4] = {0.f, 0.f, 0.f, 0.f};
    for (int k0 = 0; k0 < 64; k0 += 32) {
      if (tid < 128) {
        int r = tid >> 3;
        int kc = (tid & 7) << 2;
        *(float4*)&As[r][kc] = *(const float4*)(x + (size_t)(row0 + r) * 64 + k0 + kc);
      }
#pragma unroll
      for (int i = 0; i < 2; ++i) {
        int fidx = (i * 256 + tid) * 4;
        *(float4*)&Bs[fidx >> 6][fidx & 63] =
            *(const float4*)(lin_w + (size_t)(k0 + (fidx >> 6)) * 64 + (fidx & 63));
      }
      __syncthreads();
#pragma unroll
      for (int kk = 0; kk < 32; kk += 4) {
        float a4[4][4];
#pragma unroll
        for (int rr = 0; rr < 4; ++rr) {
          float4 t = *(const float4*)&As[g * 4 + rr][kk];
          a4[rr][0] = t.x; a4[rr][1] = t.y; a4[rr][2] = t.z; a4[rr][3] = t.w;
        }
#pragma unroll
        for (int u = 0; u < 4; ++u) {
          float bb = Bs[kk + u][lane];
#pragma unroll
          for (int rr = 0; rr < 4; ++rr) acc[rr] = fmaf(a4[rr][u], bb, acc[rr]);
        }
      }
      __syncthreads();
    }
    float bl = lin_b[lane];
#pragma unroll
    for (int rr = 0; rr < 4; ++rr) {
      int r = g * 4 + rr;
      unsigned short hv = f2bf(fmaxf(acc[rr] + bl, 0.f));
      h0[(size_t)(row0 + r) * 64 + lane] = hv;
      *(unsigned short*)(smem + ((r * 128 + lane * 2) ^ ((r & 7) << 4))) = hv;
    }
  }
  __syncthreads();
  mfma_from_lds<64>(smem, smem + 2048, bt0, xbA, as0, ad0, as4A, ad4A, row0, tid);
}

// ---------------- dispatch 3/4: fused agg(L) -> mfma(L+1) ----------------

template <int MODE>
__global__ __launch_bounds__(256) void aggmfma_kernel(
    const int* __restrict__ cnt, const int* __restrict__ slots,
    const float* __restrict__ asrcIn, const float* __restrict__ adstIn,
    const unsigned short* __restrict__ xbIn, const float* __restrict__ gbias,
    const unsigned short* __restrict__ resid, const float* __restrict__ ln_g,
    const float* __restrict__ ln_b, unsigned short* __restrict__ hOut,
    const unsigned short* __restrict__ Bt, unsigned short* __restrict__ xbOut,
    const float* __restrict__ att_src, const float* __restrict__ att_dst,
    float* __restrict__ asrcOut, float* __restrict__ adstOut) {
  __shared__ __align__(16) char smem[40960];  // ALds 8KB @0; Bsw 32KB @8192
  int tid = threadIdx.x;
  int wave = tid >> 6, lane = tid & 63;
  int row0 = blockIdx.x * 16;

  for (int nl = 0; nl < 4; ++nl) {
    int r = wave * 4 + nl;
    int n = row0 + r;
    float v[4]; int cb;
    agg_node_compute<MODE>(n, lane, cnt, slots, asrcIn, adstIn, xbIn, gbias,
                           resid, ln_g, ln_b, v, cb);
    ushort4 o;
    o.x = f2bf(v[0]); o.y = f2bf(v[1]); o.z = f2bf(v[2]); o.w = f2bf(v[3]);
    *(ushort4*)(hOut + (size_t)n * HC + cb) = o;
    *(ushort4*)(smem + (cb >> 6) * 2048 + ((r * 128 + (cb & 63) * 2) ^ ((r & 7) << 4))) = o;
  }
  __syncthreads();
  mfma_from_lds<256>(smem, smem + 8192, Bt, xbOut, att_src, att_dst,
                     asrcOut, adstOut, row0, tid);
}

// ---------------- dispatch 5: fused agg(layer2) -> FFN ----------------

__global__ __launch_bounds__(256) void aggffn_kernel(
    const int* __restrict__ cnt, const int* __restrict__ slots,
    const float* __restrict__ asrcIn, const float* __restrict__ adstIn,
    const unsigned short* __restrict__ xbIn, const float* __restrict__ gbias,
    const unsigned short* __restrict__ resid, const float* __restrict__ ln_g,
    const float* __restrict__ ln_b,
    const float* __restrict__ w1, const float* __restrict__ b1,
    const float* __restrict__ w2, const float* __restrict__ b2,
    float* __restrict__ out) {
  __shared__ __align__(16) char smem[41216];
  float (*AF)[256] = (float(*)[256])smem;            // 16KB
  float (*Bs)[128] = (float(*)[128])(smem + 16384);  // 16KB
  float (*Ms)[132] = (float(*)[132])(smem + 32768);  // 8448B
  int tid = threadIdx.x;
  int wave = tid >> 6, lane = tid & 63;
  int row0 = blockIdx.x * 16;

  for (int nl = 0; nl < 4; ++nl) {
    int r = wave * 4 + nl;
    int n = row0 + r;
    float v[4]; int cb;
    agg_node_compute<1>(n, lane, cnt, slots, asrcIn, adstIn, xbIn, gbias,
                        resid, ln_g, ln_b, v, cb);
    *(float4*)&AF[r][cb] = make_float4(v[0], v[1], v[2], v[3]);
  }
  __syncthreads();

  int g = wave;
  {  // phase 1: Ms[16][128] = relu(AF @ w1 + b1)
    int colBase = lane * 2;
    float acc[4][2];
#pragma unroll
    for (int r = 0; r < 4; ++r) { acc[r][0] = 0.f; acc[r][1] = 0.f; }
    for (int k0 = 0; k0 < 256; k0 += 32) {
#pragma unroll
      for (int i = 0; i < 4; ++i) {
        int fidx = (i * 256 + tid) * 4;
        *(float4*)&Bs[fidx >> 7][fidx & 127] =
            *(const float4*)(w1 + (size_t)(k0 + (fidx >> 7)) * 128 + (fidx & 127));
      }
      __syncthreads();
#pragma unroll
      for (int kk = 0; kk < 32; kk += 4) {
        float a4[4][4];
#pragma unroll
        for (int rr = 0; rr < 4; ++rr) {
          float4 tv = *(const float4*)&AF[g * 4 + rr][k0 + kk];
          a4[rr][0] = tv.x; a4[rr][1] = tv.y; a4[rr][2] = tv.z; a4[rr][3] = tv.w;
        }
#pragma unroll
        for (int u = 0; u < 4; ++u) {
          float2 b = *(const float2*)&Bs[kk + u][colBase];
#pragma unroll
          for (int rr = 0; rr < 4; ++rr) {
            acc[rr][0] = fmaf(a4[rr][u], b.x, acc[rr][0]);
            acc[rr][1] = fmaf(a4[rr][u], b.y, acc[rr][1]);
          }
        }
      }
      __syncthreads();
    }
    float bb0 = b1[colBase], bb1 = b1[colBase + 1];
#pragma unroll
    for (int rr = 0; rr < 4; ++rr) {
      Ms[g * 4 + rr][colBase]     = fmaxf(acc[rr][0] + bb0, 0.f);
      Ms[g * 4 + rr][colBase + 1] = fmaxf(acc[rr][1] + bb1, 0.f);
    }
  }
  __syncthreads();

  {  // phase 2: out[16][64] = Ms @ w2 + b2
    float acc[4] = {0.f, 0.f, 0.f, 0.f};
    for (int k0 = 0; k0 < 128; k0 += 32) {
#pragma unroll
      for (int i = 0; i < 2; ++i) {
        int fidx = (i * 256 + tid) * 4;
        *(float4*)&Bs[fidx >> 6][fidx & 63] =
            *(const float4*)(w2 + (size_t)(k0 + (fidx >> 6)) * 64 + (fidx & 63));
      }
      __syncthreads();
#pragma unroll
      for (int kk = 0; kk < 32; ++kk) {
        float b = Bs[kk][lane];
#pragma unroll
        for (int rr = 0; rr < 4; ++rr)
          acc[rr] = fmaf(Ms[g * 4 + rr][k0 + kk], b, acc[rr]);
      }
      __syncthreads();
    }
    float bb = b2[lane];
#pragma unroll
    for (int rr = 0; rr < 4; ++rr) {
      int row = row0 + g * 4 + rr;
      out[(size_t)row * 64 + lane] = acc[rr] + bb;
    }
  }
}

// ---------------- launch ----------------

extern "C" void kernel_launch(void* const* d_in, const int* in_sizes, int n_in,
                              void* d_out, int out_size, void* d_ws, size_t ws_size,
                              hipStream_t stream) {
  (void)in_sizes; (void)n_in; (void)out_size; (void)ws_size;
  const float* x      = (const float*)d_in[0];
  const int*   edges  = (const int*)d_in[1];
  const float* lin_w  = (const float*)d_in[2];
  const float* lin_b  = (const float*)d_in[3];
  const float* gat_w[3] = {(const float*)d_in[4], (const float*)d_in[10], (const float*)d_in[16]};
  const float* att_s[3] = {(const float*)d_in[5], (const float*)d_in[11], (const float*)d_in[17]};
  const float* att_d[3] = {(const float*)d_in[6], (const float*)d_in[12], (const float*)d_in[18]};
  const float* gat_b[3] = {(const float*)d_in[7], (const float*)d_in[13], (const float*)d_in[19]};
  const float* ln_g[3]  = {(const float*)d_in[8], (const float*)d_in[14], (const float*)d_in[20]};
  const float* ln_b[3]  = {(const float*)d_in[9], (const float*)d_in[15], (const float*)d_in[21]};
  const float* ffn_w1 = (const float*)d_in[22];
  const float* ffn_b1 = (const float*)d_in[23];
  const float* ffn_w2 = (const float*)d_in[24];
  const float* ffn_b2 = (const float*)d_in[25];

  char* p = (char*)d_ws;
  auto alloc = [&](size_t bytes) {
    char* q = p;
    p += (bytes + 255) & ~(size_t)255;
    return q;
  };
  int* cnt   = (int*)alloc(N_NODES * 4);
  int* slots = (int*)alloc((size_t)N_NODES * CAP * 4);
  unsigned short* h0 = (unsigned short*)alloc((size_t)N_NODES * 64 * 2);
  unsigned short* hA = (unsigned short*)alloc((size_t)N_NODES * HC * 2);
  unsigned short* hB = (unsigned short*)alloc((size_t)N_NODES * HC * 2);
  unsigned short* xbA = (unsigned short*)alloc((size_t)N_NODES * HC * 2);
  unsigned short* xbB = (unsigned short*)alloc((size_t)N_NODES * HC * 2);
  float* as4A = (float*)alloc((size_t)N_NODES * 16);
  float* ad4A = (float*)alloc((size_t)N_NODES * 16);
  float* as4B = (float*)alloc((size_t)N_NODES * 16);
  float* ad4B = (float*)alloc((size_t)N_NODES * 16);
  unsigned short* bt0 = (unsigned short*)alloc(256 * 64 * 2);
  unsigned short* bt1 = (unsigned short*)alloc(256 * 256 * 2);
  unsigned short* bt2 = (unsigned short*)alloc(256 * 256 * 2);

  const int gblk = N_NODES / 16;  // 625

  prep_kernel<<<328, 256, 0, stream>>>(cnt, gat_w[0], bt0, gat_w[1], bt1, gat_w[2], bt2);
  scatter_linmfma<<<1290 + gblk, 256, 0, stream>>>(edges, cnt, slots, x, lin_w, lin_b,
                                                   h0, bt0, att_s[0], att_d[0],
                                                   xbA, as4A, ad4A);
  aggmfma_kernel<0><<<gblk, 256, 0, stream>>>(cnt, slots, as4A, ad4A, xbA, gat_b[0],
                                              h0, ln_g[0], ln_b[0], hA,
                                              bt1, xbB, att_s[1], att_d[1], as4B, ad4B);
  aggmfma_kernel<1><<<gblk, 256, 0, stream>>>(cnt, slots, as4B, ad4B, xbB, gat_b[1],
                                              hA, ln_g[1], ln_b[1], hB,
                                              bt2, xbA, att_s[2], att_d[2], as4A, ad4A);
  aggffn_kernel<<<gblk, 256, 0, stream>>>(cnt, slots, as4A, ad4A, xbA, gat_b[2],
                                          hB, ln_g[2], ln_b[2],
                                          ffn_w1, ffn_b1, ffn_w2, ffn_b2, (float*)d_out);
}

// Round 23
// 149.068 us; speedup vs baseline: 1.2434x; 1.0164x over previous
//
#include <hip/hip_runtime.h>

#define N_NODES 10000
#define N_EDGES 320000
#define EL (N_EDGES + N_NODES)
#define HC 256
#define CAP 96

using bf16x8 = __attribute__((ext_vector_type(8))) short;
using f32x4  = __attribute__((ext_vector_type(4))) float;

__device__ __forceinline__ float bf2f(unsigned short u) {
  union { unsigned int i; float f; } v; v.i = ((unsigned int)u) << 16; return v.f;
}
__device__ __forceinline__ unsigned short f2bf(float f) {
  union { float f; unsigned int i; } v; v.f = f;
  unsigned int r = (v.i + 0x7FFFu + ((v.i >> 16) & 1u)) >> 16;
  return (unsigned short)r;
}

// ---------------- prep: zero cnt + transpose/convert 3 weight mats (328 blocks) --------

__device__ __forceinline__ void convw_body(const float* __restrict__ w,
                                           unsigned short* __restrict__ bt,
                                           int K, int idx) {
  int half = K >> 1;
  int col = idx / half;
  int k2 = (idx % half) * 2;
  ushort2 o;
  o.x = f2bf(w[(size_t)k2 * 256 + col]);
  o.y = f2bf(w[(size_t)(k2 + 1) * 256 + col]);
  *(ushort2*)(bt + (size_t)col * K + k2) = o;
}

__global__ __launch_bounds__(256) void prep_kernel(
    int* __restrict__ cnt,
    const float* __restrict__ w0, unsigned short* __restrict__ bt0,
    const float* __restrict__ w1, unsigned short* __restrict__ bt1,
    const float* __restrict__ w2, unsigned short* __restrict__ bt2) {
  int b = blockIdx.x, tid = threadIdx.x;
  if (b < 40) {
    int i = b * 256 + tid;
    if (i < N_NODES) cnt[i] = 0;
  } else if (b < 72) {
    convw_body(w0, bt0, 64, (b - 40) * 256 + tid);
  } else if (b < 200) {
    convw_body(w1, bt1, 256, (b - 72) * 256 + tid);
  } else {
    convw_body(w2, bt2, 256, (b - 200) * 256 + tid);
  }
}

// ---------------- MFMA phase with A already in LDS (K/64 slices of 2048B, XOR-swizzled) --

template <int K>
__device__ void mfma_from_lds(const char* ALds, char* Bsw,
                              const unsigned short* __restrict__ Bt,
                              unsigned short* __restrict__ Cb,
                              const float* __restrict__ att_src,
                              const float* __restrict__ att_dst,
                              float* __restrict__ asrc_out, float* __restrict__ adst_out,
                              int row0, int tid) {
  int wave = tid >> 6, lane = tid & 63;
  int r = lane & 15, g = lane >> 4;

  f32x4 acc[4];
#pragma unroll
  for (int i = 0; i < 4; ++i) acc[i] = {0.f, 0.f, 0.f, 0.f};

  for (int k0 = 0; k0 < K; k0 += 64) {
#pragma unroll
    for (int i = 0; i < 8; ++i) {  // stage B slice: 256 cols x 64 k bf16 (32KB)
      int idx = i * 256 + tid;
      int col = idx >> 3;
      int kc8 = idx & 7;
      uint4 v = *(const uint4*)(Bt + (size_t)col * K + k0 + kc8 * 8);
      *(uint4*)(Bsw + ((col * 128 + kc8 * 16) ^ ((col & 7) << 4))) = v;
    }
    __syncthreads();
    const char* Asl = ALds + (k0 >> 6) * 2048;
#pragma unroll
    for (int chunk = 0; chunk < 2; ++chunk) {
      bf16x8 af = *(const bf16x8*)(Asl + ((r * 128 + chunk * 64 + g * 16) ^ ((r & 7) << 4)));
#pragma unroll
      for (int i = 0; i < 4; ++i) {
        int col = (wave * 4 + i) * 16 + r;
        bf16x8 bfr = *(const bf16x8*)(Bsw + ((col * 128 + chunk * 64 + g * 16) ^ ((col & 7) << 4)));
        acc[i] = __builtin_amdgcn_mfma_f32_16x16x32_bf16(af, bfr, acc[i], 0, 0, 0);
      }
    }
    __syncthreads();
  }

  float asv[4], adv[4];
#pragma unroll
  for (int i = 0; i < 4; ++i) {
    int col = (wave * 4 + i) * 16 + r;
    asv[i] = att_src[col];
    adv[i] = att_dst[col];
  }
#pragma unroll
  for (int j = 0; j < 4; ++j) {
    float ps = acc[0][j] * asv[0] + acc[1][j] * asv[1] + acc[2][j] * asv[2] + acc[3][j] * asv[3];
    float pd = acc[0][j] * adv[0] + acc[1][j] * adv[1] + acc[2][j] * adv[2] + acc[3][j] * adv[3];
#pragma unroll
    for (int m = 8; m >= 1; m >>= 1) {
      ps += __shfl_xor(ps, m);
      pd += __shfl_xor(pd, m);
    }
    if (r == 0) {
      int row = row0 + g * 4 + j;
      asrc_out[row * 4 + wave] = ps;
      adst_out[row * 4 + wave] = pd;
    }
  }

#pragma unroll
  for (int i = 0; i < 4; ++i) {
    int col = (wave * 4 + i) * 16 + r;
#pragma unroll
    for (int j = 0; j < 4; ++j) {
      int row = row0 + g * 4 + j;
      Cb[(size_t)row * 256 + col] = f2bf(acc[i][j]);
    }
  }
}

// ---------------- agg for ONE node (full wave; half-wave edge split; chunk-4) ----------

template <int MODE>
__device__ __forceinline__ void agg_node_compute(
    int n, int lane,
    const int* __restrict__ cnt, const int* __restrict__ slots,
    const float* __restrict__ asrc, const float* __restrict__ adst,
    const unsigned short* __restrict__ xb, const float* __restrict__ bias,
    const unsigned short* __restrict__ resid,
    const float* __restrict__ ln_g, const float* __restrict__ ln_b,
    float v[4], int& cbOut) {
  int lh = lane & 31;
  int half = lane >> 5;
  int h = lh >> 3;
  int ch8 = lh << 3;
  float ad = adst[n * 4 + h];

  int i0 = n * CAP;
  int deg = cnt[n];
  int len0 = (deg + 1) >> 1;
  int beg = i0 + (half ? len0 : 0);
  int end = i0 + (half ? deg : len0);
  int last = end - 1;

  float a0 = 0.f, a1 = 0.f, a2 = 0.f, a3 = 0.f, a4 = 0.f, a5 = 0.f, a6 = 0.f, a7 = 0.f;
  float wsum = 0.f;

  int sA[4];
#pragma unroll
  for (int j = 0; j < 4; ++j) sA[j] = slots[min(beg + j, last)];
  float ca[4]; uint4 cx[4];
#pragma unroll
  for (int j = 0; j < 4; ++j) {
    ca[j] = asrc[sA[j] * 4 + h];
    cx[j] = *(const uint4*)(xb + (size_t)sA[j] * HC + ch8);
  }
#pragma unroll
  for (int j = 0; j < 4; ++j) sA[j] = slots[min(beg + 4 + j, last)];

  for (int base = beg; base < end; base += 4) {
    float na[4]; uint4 nx[4];
#pragma unroll
    for (int j = 0; j < 4; ++j) {
      na[j] = asrc[sA[j] * 4 + h];
      nx[j] = *(const uint4*)(xb + (size_t)sA[j] * HC + ch8);
    }
#pragma unroll
    for (int j = 0; j < 4; ++j) sA[j] = slots[min(base + 8 + j, last)];
#pragma unroll
    for (int j = 0; j < 4; ++j) {
      float e = ca[j] + ad;
      e = e > 0.f ? e : 0.2f * e;
      float wg = __expf(e);
      wg = (base + j < end) ? wg : 0.f;
      wsum += wg;
      a0 = fmaf(wg, bf2f((unsigned short)(cx[j].x & 0xffff)), a0);
      a1 = fmaf(wg, bf2f((unsigned short)(cx[j].x >> 16)), a1);
      a2 = fmaf(wg, bf2f((unsigned short)(cx[j].y & 0xffff)), a2);
      a3 = fmaf(wg, bf2f((unsigned short)(cx[j].y >> 16)), a3);
      a4 = fmaf(wg, bf2f((unsigned short)(cx[j].z & 0xffff)), a4);
      a5 = fmaf(wg, bf2f((unsigned short)(cx[j].z >> 16)), a5);
      a6 = fmaf(wg, bf2f((unsigned short)(cx[j].w & 0xffff)), a6);
      a7 = fmaf(wg, bf2f((unsigned short)(cx[j].w >> 16)), a7);
    }
#pragma unroll
    for (int j = 0; j < 4; ++j) { ca[j] = na[j]; cx[j] = nx[j]; }
  }

  a0 += __shfl_xor(a0, 32); a1 += __shfl_xor(a1, 32);
  a2 += __shfl_xor(a2, 32); a3 += __shfl_xor(a3, 32);
  a4 += __shfl_xor(a4, 32); a5 += __shfl_xor(a5, 32);
  a6 += __shfl_xor(a6, 32); a7 += __shfl_xor(a7, 32);
  wsum += __shfl_xor(wsum, 32);

  int cb = ch8 + half * 4;
  float v0 = half ? a4 : a0;
  float v1 = half ? a5 : a1;
  float v2 = half ? a6 : a2;
  float v3 = half ? a7 : a3;

  float rw = 1.f / wsum;
  float4 b4 = *(const float4*)(bias + cb);
  v0 = fmaf(v0, rw, b4.x);
  v1 = fmaf(v1, rw, b4.y);
  v2 = fmaf(v2, rw, b4.z);
  v3 = fmaf(v3, rw, b4.w);
  v0 = v0 > 0.f ? v0 : __expf(v0) - 1.f;
  v1 = v1 > 0.f ? v1 : __expf(v1) - 1.f;
  v2 = v2 > 0.f ? v2 : __expf(v2) - 1.f;
  v3 = v3 > 0.f ? v3 : __expf(v3) - 1.f;

  if constexpr (MODE == 0) {
    if (cb < 64) {
      ushort4 r4 = *(const ushort4*)(resid + (size_t)n * 64 + cb);
      v0 += bf2f(r4.x); v1 += bf2f(r4.y); v2 += bf2f(r4.z); v3 += bf2f(r4.w);
    }
  } else {
    ushort4 r4 = *(const ushort4*)(resid + (size_t)n * HC + cb);
    v0 += bf2f(r4.x); v1 += bf2f(r4.y); v2 += bf2f(r4.z); v3 += bf2f(r4.w);
  }

  float s1 = v0 + v1 + v2 + v3;
  float s2 = v0 * v0 + v1 * v1 + v2 * v2 + v3 * v3;
#pragma unroll
  for (int m = 32; m >= 1; m >>= 1) {
    s1 += __shfl_xor(s1, m);
    s2 += __shfl_xor(s2, m);
  }
  float mean = s1 * (1.f / 256.f);
  float var = s2 * (1.f / 256.f) - mean * mean;
  float inv = rsqrtf(var + 1e-5f);

  float4 g4 = *(const float4*)(ln_g + cb);
  float4 lb4 = *(const float4*)(ln_b + cb);
  v[0] = (v0 - mean) * inv * g4.x + lb4.x;
  v[1] = (v1 - mean) * inv * g4.y + lb4.y;
  v[2] = (v2 - mean) * inv * g4.z + lb4.z;
  v[3] = (v3 - mean) * inv * g4.w + lb4.w;
  cbOut = cb;
}

// ---------------- standalone agg (wave per node, 2500 blocks): hout bf16 --------------

template <int MODE>
__global__ __launch_bounds__(256) void agg_kernel(
    const int* __restrict__ cnt, const int* __restrict__ slots,
    const float* __restrict__ asrc, const float* __restrict__ adst,
    const unsigned short* __restrict__ xb, const float* __restrict__ bias,
    const unsigned short* __restrict__ resid, const float* __restrict__ ln_g,
    const float* __restrict__ ln_b, unsigned short* __restrict__ hout) {
  int w = threadIdx.x >> 6, lane = threadIdx.x & 63;
  int n = blockIdx.x * 4 + w;
  float v[4]; int cb;
  agg_node_compute<MODE>(n, lane, cnt, slots, asrc, adst, xb, bias,
                         resid, ln_g, ln_b, v, cb);
  ushort4 o;
  o.x = f2bf(v[0]); o.y = f2bf(v[1]); o.z = f2bf(v[2]); o.w = f2bf(v[3]);
  *(ushort4*)(hout + (size_t)n * HC + cb) = o;
}

// ---------------- dispatch 2: edge scatter + fused lin->mfma0 ----------------

__global__ __launch_bounds__(256) void scatter_linmfma(
    const int* __restrict__ edges, int* __restrict__ cnt, int* __restrict__ slots,
    const float* __restrict__ x, const float* __restrict__ lin_w,
    const float* __restrict__ lin_b, unsigned short* __restrict__ h0,
    const unsigned short* __restrict__ bt0,
    const float* __restrict__ as0, const float* __restrict__ ad0,
    unsigned short* __restrict__ xbA, float* __restrict__ as4A, float* __restrict__ ad4A) {
  __shared__ __align__(16) char smem[34816];
  int tid = threadIdx.x;
  int b = blockIdx.x;
  if (b < 1290) {
    int e = b * 256 + tid;
    if (e >= EL) return;
    int s, d;
    if (e < N_EDGES) { s = edges[e]; d = edges[N_EDGES + e]; }
    else { s = d = e - N_EDGES; }
    int pos = atomicAdd(&cnt[d], 1);
    slots[d * CAP + pos] = s;
    return;
  }
  int row0 = (b - 1290) * 16;
  int g = tid >> 6, lane = tid & 63;
  {
    float (*As)[36] = (float(*)[36])(smem + 2048);
    float (*Bs)[64] = (float(*)[64])(smem + 2048 + 2304);
    float acc[4] = {0.f, 0.f, 0.f, 0.f};
    for (int k0 = 0; k0 < 64; k0 += 32) {
      if (tid < 128) {
        int r = tid >> 3;
        int kc = (tid & 7) << 2;
        *(float4*)&As[r][kc] = *(const float4*)(x + (size_t)(row0 + r) * 64 + k0 + kc);
      }
#pragma unroll
      for (int i = 0; i < 2; ++i) {
        int fidx = (i * 256 + tid) * 4;
        *(float4*)&Bs[fidx >> 6][fidx & 63] =
            *(const float4*)(lin_w + (size_t)(k0 + (fidx >> 6)) * 64 + (fidx & 63));
      }
      __syncthreads();
#pragma unroll
      for (int kk = 0; kk < 32; kk += 4) {
        float a4[4][4];
#pragma unroll
        for (int rr = 0; rr < 4; ++rr) {
          float4 t = *(const float4*)&As[g * 4 + rr][kk];
          a4[rr][0] = t.x; a4[rr][1] = t.y; a4[rr][2] = t.z; a4[rr][3] = t.w;
        }
#pragma unroll
        for (int u = 0; u < 4; ++u) {
          float bb = Bs[kk + u][lane];
#pragma unroll
          for (int rr = 0; rr < 4; ++rr) acc[rr] = fmaf(a4[rr][u], bb, acc[rr]);
        }
      }
      __syncthreads();
    }
    float bl = lin_b[lane];
#pragma unroll
    for (int rr = 0; rr < 4; ++rr) {
      int r = g * 4 + rr;
      unsigned short hv = f2bf(fmaxf(acc[rr] + bl, 0.f));
      h0[(size_t)(row0 + r) * 64 + lane] = hv;
      *(unsigned short*)(smem + ((r * 128 + lane * 2) ^ ((r & 7) << 4))) = hv;
    }
  }
  __syncthreads();
  mfma_from_lds<64>(smem, smem + 2048, bt0, xbA, as0, ad0, as4A, ad4A, row0, tid);
}

// ---------------- dispatch 3/4: fused agg(L) -> mfma(L+1) ----------------

template <int MODE>
__global__ __launch_bounds__(256) void aggmfma_kernel(
    const int* __restrict__ cnt, const int* __restrict__ slots,
    const float* __restrict__ asrcIn, const float* __restrict__ adstIn,
    const unsigned short* __restrict__ xbIn, const float* __restrict__ gbias,
    const unsigned short* __restrict__ resid, const float* __restrict__ ln_g,
    const float* __restrict__ ln_b, unsigned short* __restrict__ hOut,
    const unsigned short* __restrict__ Bt, unsigned short* __restrict__ xbOut,
    const float* __restrict__ att_src, const float* __restrict__ att_dst,
    float* __restrict__ asrcOut, float* __restrict__ adstOut) {
  __shared__ __align__(16) char smem[40960];  // ALds 8KB @0; Bsw 32KB @8192
  int tid = threadIdx.x;
  int wave = tid >> 6, lane = tid & 63;
  int row0 = blockIdx.x * 16;

  for (int nl = 0; nl < 4; ++nl) {
    int r = wave * 4 + nl;
    int n = row0 + r;
    float v[4]; int cb;
    agg_node_compute<MODE>(n, lane, cnt, slots, asrcIn, adstIn, xbIn, gbias,
                           resid, ln_g, ln_b, v, cb);
    ushort4 o;
    o.x = f2bf(v[0]); o.y = f2bf(v[1]); o.z = f2bf(v[2]); o.w = f2bf(v[3]);
    *(ushort4*)(hOut + (size_t)n * HC + cb) = o;
    *(ushort4*)(smem + (cb >> 6) * 2048 + ((r * 128 + (cb & 63) * 2) ^ ((r & 7) << 4))) = o;
  }
  __syncthreads();
  mfma_from_lds<256>(smem, smem + 8192, Bt, xbOut, att_src, att_dst,
                     asrcOut, adstOut, row0, tid);
}

// ---------------- standalone FFN: out = relu(hA@w1+b1)@w2 + b2 (hA bf16) --------------

__global__ __launch_bounds__(256) void ffn_kernel(const unsigned short* __restrict__ A,
                                                  const float* __restrict__ w1,
                                                  const float* __restrict__ b1,
                                                  const float* __restrict__ w2,
                                                  const float* __restrict__ b2,
                                                  float* __restrict__ out) {
  __shared__ float As[16][36];
  __shared__ float Bs[32][128];
  __shared__ float Ms[16][132];
  int tid = threadIdx.x;
  int row0 = blockIdx.x * 16;
  int g = tid >> 6, lane = tid & 63;

  {
    int colBase = lane * 2;
    float acc[4][2];
#pragma unroll
    for (int r = 0; r < 4; ++r) { acc[r][0] = 0.f; acc[r][1] = 0.f; }
    for (int k0 = 0; k0 < 256; k0 += 32) {
      if (tid < 128) {
        int r = tid >> 3;
        int kc = (tid & 7) << 2;
        ushort4 av = *(const ushort4*)(A + (size_t)(row0 + r) * 256 + k0 + kc);
        As[r][kc]     = bf2f(av.x);
        As[r][kc + 1] = bf2f(av.y);
        As[r][kc + 2] = bf2f(av.z);
        As[r][kc + 3] = bf2f(av.w);
      }
#pragma unroll
      for (int i = 0; i < 4; ++i) {
        int fidx = (i * 256 + tid) * 4;
        *(float4*)&Bs[fidx >> 7][fidx & 127] =
            *(const float4*)(w1 + (size_t)(k0 + (fidx >> 7)) * 128 + (fidx & 127));
      }
      __syncthreads();
#pragma unroll
      for (int kk = 0; kk < 32; kk += 4) {
        float a4[4][4];
#pragma unroll
        for (int rr = 0; rr < 4; ++rr) {
          float4 tv = *(const float4*)&As[g * 4 + rr][kk];
          a4[rr][0] = tv.x; a4[rr][1] = tv.y; a4[rr][2] = tv.z; a4[rr][3] = tv.w;
        }
#pragma unroll
        for (int u = 0; u < 4; ++u) {
          float2 b = *(const float2*)&Bs[kk + u][colBase];
#pragma unroll
          for (int rr = 0; rr < 4; ++rr) {
            acc[rr][0] = fmaf(a4[rr][u], b.x, acc[rr][0]);
            acc[rr][1] = fmaf(a4[rr][u], b.y, acc[rr][1]);
          }
        }
      }
      __syncthreads();
    }
    float bb0 = b1[colBase], bb1 = b1[colBase + 1];
#pragma unroll
    for (int rr = 0; rr < 4; ++rr) {
      Ms[g * 4 + rr][colBase]     = fmaxf(acc[rr][0] + bb0, 0.f);
      Ms[g * 4 + rr][colBase + 1] = fmaxf(acc[rr][1] + bb1, 0.f);
    }
  }
  __syncthreads();

  {
    float acc[4] = {0.f, 0.f, 0.f, 0.f};
    for (int k0 = 0; k0 < 128; k0 += 32) {
#pragma unroll
      for (int i = 0; i < 2; ++i) {
        int fidx = (i * 256 + tid) * 4;
        *(float4*)&Bs[fidx >> 6][fidx & 63] =
            *(const float4*)(w2 + (size_t)(k0 + (fidx >> 6)) * 64 + (fidx & 63));
      }
      __syncthreads();
#pragma unroll
      for (int kk = 0; kk < 32; ++kk) {
        float b = Bs[kk][lane];
#pragma unroll
        for (int rr = 0; rr < 4; ++rr)
          acc[rr] = fmaf(Ms[g * 4 + rr][k0 + kk], b, acc[rr]);
      }
      __syncthreads();
    }
    float bb = b2[lane];
#pragma unroll
    for (int rr = 0; rr < 4; ++rr) {
      int row = row0 + g * 4 + rr;
      out[(size_t)row * 64 + lane] = acc[rr] + bb;
    }
  }
}

// ---------------- launch ----------------

extern "C" void kernel_launch(void* const* d_in, const int* in_sizes, int n_in,
                              void* d_out, int out_size, void* d_ws, size_t ws_size,
                              hipStream_t stream) {
  (void)in_sizes; (void)n_in; (void)out_size; (void)ws_size;
  const float* x      = (const float*)d_in[0];
  const int*   edges  = (const int*)d_in[1];
  const float* lin_w  = (const float*)d_in[2];
  const float* lin_b  = (const float*)d_in[3];
  const float* gat_w[3] = {(const float*)d_in[4], (const float*)d_in[10], (const float*)d_in[16]};
  const float* att_s[3] = {(const float*)d_in[5], (const float*)d_in[11], (const float*)d_in[17]};
  const float* att_d[3] = {(const float*)d_in[6], (const float*)d_in[12], (const float*)d_in[18]};
  const float* gat_b[3] = {(const float*)d_in[7], (const float*)d_in[13], (const float*)d_in[19]};
  const float* ln_g[3]  = {(const float*)d_in[8], (const float*)d_in[14], (const float*)d_in[20]};
  const float* ln_b[3]  = {(const float*)d_in[9], (const float*)d_in[15], (const float*)d_in[21]};
  const float* ffn_w1 = (const float*)d_in[22];
  const float* ffn_b1 = (const float*)d_in[23];
  const float* ffn_w2 = (const float*)d_in[24];
  const float* ffn_b2 = (const float*)d_in[25];

  char* p = (char*)d_ws;
  auto alloc = [&](size_t bytes) {
    char* q = p;
    p += (bytes + 255) & ~(size_t)255;
    return q;
  };
  int* cnt   = (int*)alloc(N_NODES * 4);
  int* slots = (int*)alloc((size_t)N_NODES * CAP * 4);
  unsigned short* h0 = (unsigned short*)alloc((size_t)N_NODES * 64 * 2);
  unsigned short* hA = (unsigned short*)alloc((size_t)N_NODES * HC * 2);
  unsigned short* hB = (unsigned short*)alloc((size_t)N_NODES * HC * 2);
  unsigned short* xbA = (unsigned short*)alloc((size_t)N_NODES * HC * 2);
  unsigned short* xbB = (unsigned short*)alloc((size_t)N_NODES * HC * 2);
  float* as4A = (float*)alloc((size_t)N_NODES * 16);
  float* ad4A = (float*)alloc((size_t)N_NODES * 16);
  float* as4B = (float*)alloc((size_t)N_NODES * 16);
  float* ad4B = (float*)alloc((size_t)N_NODES * 16);
  unsigned short* bt0 = (unsigned short*)alloc(256 * 64 * 2);
  unsigned short* bt1 = (unsigned short*)alloc(256 * 256 * 2);
  unsigned short* bt2 = (unsigned short*)alloc(256 * 256 * 2);

  const int gblk = N_NODES / 16;  // 625
  const int nblk = N_NODES / 4;   // 2500

  prep_kernel<<<328, 256, 0, stream>>>(cnt, gat_w[0], bt0, gat_w[1], bt1, gat_w[2], bt2);
  scatter_linmfma<<<1290 + gblk, 256, 0, stream>>>(edges, cnt, slots, x, lin_w, lin_b,
                                                   h0, bt0, att_s[0], att_d[0],
                                                   xbA, as4A, ad4A);
  aggmfma_kernel<0><<<gblk, 256, 0, stream>>>(cnt, slots, as4A, ad4A, xbA, gat_b[0],
                                              h0, ln_g[0], ln_b[0], hA,
                                              bt1, xbB, att_s[1], att_d[1], as4B, ad4B);
  aggmfma_kernel<1><<<gblk, 256, 0, stream>>>(cnt, slots, as4B, ad4B, xbB, gat_b[1],
                                              hA, ln_g[1], ln_b[1], hB,
                                              bt2, xbA, att_s[2], att_d[2], as4A, ad4A);
  // D5: standalone agg2 (wave per node; hA is free after D4) then FFN
  agg_kernel<1><<<nblk, 256, 0, stream>>>(cnt, slots, as4A, ad4A, xbA, gat_b[2],
                                          hB, ln_g[2], ln_b[2], hA);
  ffn_kernel<<<gblk, 256, 0, stream>>>(hA, ffn_w1, ffn_b1, ffn_w2, ffn_b2, (float*)d_out);
}